// Round 7
// baseline (322.494 us; speedup 1.0000x reference)
//
#include <hip/hip_runtime.h>
#include <stdint.h>

#define B 8
#define F 8192
#define C 256
#define K 4
#define P (F / 4)     // 2048
#define CAP 16        // max tracked incoming collapsed faces per target
#define NBIN 16384
#define BIN_SHIFT 18  // bin = float_bits >> 18 (w >= 0 -> monotonic)

// ---------------------------------------------------------------------------
// kZ: zero the contiguous [hist | cnt | flag] region (1 MiB) with int4 stores.
// ---------------------------------------------------------------------------
__global__ __launch_bounds__(256) void kZ(int4* __restrict__ z) {
    z[blockIdx.x * 256 + threadIdx.x] = make_int4(0, 0, 0, 0);
}

// ---------------------------------------------------------------------------
// kW: one wave per face — gather K=4 ring rows, mean, L2 norm -> w.
// Lane 0 also bumps the per-batch histogram with ONE non-returning global
// atomic (scattered across the device; replaces the 8-block LDS histogram
// whose hot-bin serialization dominated R6's kSEL).
// ---------------------------------------------------------------------------
__global__ __launch_bounds__(256) void kW(const float* __restrict__ feat,
                                          const int* __restrict__ ring,
                                          float* __restrict__ w,
                                          int* __restrict__ hist) {
    const int wid  = blockIdx.x * 4 + (threadIdx.x >> 6);  // [0, B*F)
    const int lane = threadIdx.x & 63;
    const int b    = wid >> 13;

    const int rbase = wid * K;
    const int r0 = ring[rbase + 0], r1 = ring[rbase + 1];
    const int r2 = ring[rbase + 2], r3 = ring[rbase + 3];
    const float4* f4 = (const float4*)feat;
    const size_t base = (size_t)b * F;
    const int    CW   = C / 4;
    const float4 v0 = f4[(base + r0) * CW + lane];
    const float4 v1 = f4[(base + r1) * CW + lane];
    const float4 v2 = f4[(base + r2) * CW + lane];
    const float4 v3 = f4[(base + r3) * CW + lane];

    float4 a;
    a.x = (v0.x + v1.x) + (v2.x + v3.x);
    a.y = (v0.y + v1.y) + (v2.y + v3.y);
    a.z = (v0.z + v1.z) + (v2.z + v3.z);
    a.w = (v0.w + v1.w) + (v2.w + v3.w);
    float s = (a.x * a.x + a.y * a.y + a.z * a.z + a.w * a.w) * 0.0625f;
#pragma unroll
    for (int off = 32; off > 0; off >>= 1) s += __shfl_down(s, off, 64);
    if (lane == 0) {
        const float val = sqrtf(s);
        w[wid] = val;
        const uint32_t bin = __float_as_uint(val) >> BIN_SHIFT;
        atomicAdd(&hist[b * NBIN + (int)bin], 1);   // non-returning, fire&forget
    }
}

// ---------------------------------------------------------------------------
// kT: per-batch scan of 16384 bins -> threshold bin T (bin holding rank P-1)
// and R = P - count_below(T). Zeroes ccnt[b] for kFL.
// ---------------------------------------------------------------------------
__global__ __launch_bounds__(256) void kT(const int* __restrict__ hist,
                                          int* __restrict__ tbin,
                                          int* __restrict__ trank,
                                          int* __restrict__ ccnt) {
    __shared__ int part[256];
    const int b = blockIdx.x;
    const int* h = hist + (size_t)b * NBIN;
    const int t = threadIdx.x;
    if (t == 0) ccnt[b] = 0;
    int s = 0;
#pragma unroll 8
    for (int i = 0; i < 64; ++i) s += h[t * 64 + i];
    part[t] = s;
    __syncthreads();
    for (int off = 1; off < 256; off <<= 1) {               // inclusive scan
        const int v = part[t];
        const int u = (t >= off) ? part[t - off] : 0;
        __syncthreads();
        part[t] = v + u;
        __syncthreads();
    }
    const int excl = (t == 0) ? 0 : part[t - 1];
    if (P - 1 >= excl && P - 1 < part[t]) {                 // exactly one thread
        int c = excl;
        for (int i = 0; i < 64; ++i) {
            const int hv = h[t * 64 + i];
            if (P - 1 < c + hv) { tbin[b] = t * 64 + i; trank[b] = P - c; break; }
            c += hv;
        }
    }
}

// ---------------------------------------------------------------------------
// kFL: 256 blocks, one block per 256 faces of a single batch.
// bin < T  -> flag + push into 3 adjacency incoming lists.
// bin == T -> LDS-compact candidates, ONE ccnt atomic per block, coalesced
// copy to global cand (R4 design — avoids same-address atomic serialization).
// ---------------------------------------------------------------------------
__global__ __launch_bounds__(256) void kFL(const float* __restrict__ w,
                                           const int* __restrict__ adj,
                                           const int* __restrict__ tbin,
                                           int* __restrict__ flag,
                                           int* __restrict__ cnt,
                                           int* __restrict__ srcs,
                                           unsigned long long* __restrict__ cand,
                                           int* __restrict__ ccnt) {
    __shared__ unsigned long long lc[256];
    __shared__ int lcnt;
    __shared__ int lbase;
    if (threadIdx.x == 0) lcnt = 0;
    __syncthreads();

    const int t = blockIdx.x * 256 + threadIdx.x;           // [0, B*F)
    const int b = t >> 13;                                  // block spans one batch
    const uint32_t bits = __float_as_uint(w[t]);
    const int bin = (int)(bits >> BIN_SHIFT);
    const int T = tbin[b];
    if (bin < T) {
        flag[t] = 1;
#pragma unroll
        for (int j = 0; j < 3; ++j) {
            const int n    = adj[(size_t)t * 3 + j];
            const int tgt  = b * F + n;
            const int slot = atomicAdd(&cnt[tgt], 1);
            if (slot < CAP) srcs[(size_t)tgt * CAP + slot] = t;
        }
    } else if (bin == T) {
        const int pos = atomicAdd(&lcnt, 1);                // LDS atomic: cheap
        lc[pos] = ((unsigned long long)bits << 32) | (uint32_t)(t & (F - 1));
    }
    __syncthreads();
    if (threadIdx.x == 0 && lcnt > 0)
        lbase = atomicAdd(&ccnt[b], lcnt);                  // 1 contended op/block
    __syncthreads();
    const int m = lcnt;
    for (int i = threadIdx.x; i < m; i += 256)
        cand[(size_t)b * F + lbase + i] = lc[i];
}

// ---------------------------------------------------------------------------
// kSel: per batch — exact rank of boundary candidates by O(n^2) counting
// (keys distinct via idx bits). LDS broadcast reads; rank < R -> flag+push.
// ---------------------------------------------------------------------------
__global__ __launch_bounds__(1024) void kSel(const int* __restrict__ ccnt,
                                             const int* __restrict__ trank,
                                             const unsigned long long* __restrict__ cand,
                                             const int* __restrict__ adj,
                                             int* __restrict__ flag,
                                             int* __restrict__ cnt,
                                             int* __restrict__ srcs) {
    __shared__ unsigned long long keys[F];                  // 64 KiB
    const int b = blockIdx.x;
    const int n = ccnt[b];
    const int R = trank[b];
    for (int i = threadIdx.x; i < n; i += 1024)
        keys[i] = cand[(size_t)b * F + i];
    __syncthreads();
    for (int i = threadIdx.x; i < n; i += 1024) {
        const unsigned long long my = keys[i];
        int rank = 0;
        for (int j = 0; j < n; ++j) rank += (keys[j] < my) ? 1 : 0;
        if (rank < R) {
            const int t = b * F + (int)(uint32_t)my;
            flag[t] = 1;
#pragma unroll
            for (int j = 0; j < 3; ++j) {
                const int nb   = adj[(size_t)t * 3 + j];
                const int tgt  = b * F + nb;
                const int slot = atomicAdd(&cnt[tgt], 1);
                if (slot < CAP) srcs[(size_t)tgt * CAP + slot] = t;
            }
        }
    }
}

// ---------------------------------------------------------------------------
// kG: one wave per face — fused merge + normalize + erase.
// ---------------------------------------------------------------------------
__global__ __launch_bounds__(256) void kG(const float* __restrict__ feat,
                                          const int* __restrict__ cnt,
                                          const int* __restrict__ flag,
                                          const int* __restrict__ srcs,
                                          float* __restrict__ out) {
    const int wid  = blockIdx.x * 4 + (threadIdx.x >> 6);
    const int lane = threadIdx.x & 63;
    float4* drow = (float4*)(out + (size_t)wid * C);

    if (flag[wid]) {
        drow[lane] = make_float4(0.f, 0.f, 0.f, 0.f);
        return;
    }
    const int m  = cnt[wid];
    const int mm = m < CAP ? m : CAP;

    float4 acc = ((const float4*)(feat + (size_t)wid * C))[lane];
    const float inv3 = 1.0f / 3.0f;
    for (int i = 0; i < mm; ++i) {
        const int s = srcs[(size_t)wid * CAP + i];
        const float4 v = ((const float4*)(feat + (size_t)s * C))[lane];
        acc.x += v.x * inv3; acc.y += v.y * inv3;
        acc.z += v.z * inv3; acc.w += v.w * inv3;
    }
    const float inv = 1.0f / (1.0f + (float)m);
    acc.x *= inv; acc.y *= inv; acc.z *= inv; acc.w *= inv;
    drow[lane] = acc;
}

extern "C" void kernel_launch(void* const* d_in, const int* in_sizes, int n_in,
                              void* d_out, int out_size, void* d_ws, size_t ws_size,
                              hipStream_t stream) {
    const float* feat = (const float*)d_in[0];
    const int*   adj  = (const int*)d_in[1];
    const int*   ring = (const int*)d_in[2];
    float* out = (float*)d_out;

    // ws layout: cand (8B-aligned) | w | [hist | cnt | flag] (contiguous zero
    // region for kZ) | srcs | ccnt | tbin | trank
    unsigned long long* cand = (unsigned long long*)d_ws;   // B*F (512 KiB)
    float* w    = (float*)(cand + B * F);                   // B*F
    int*   hist = (int*)(w + B * F);                        // B*NBIN (512 KiB)
    int*   cnt  = hist + B * NBIN;                          // B*F (256 KiB)
    int*   flag = cnt + B * F;                              // B*F (256 KiB)
    int*   srcs = flag + B * F;                             // B*F*CAP (4 MiB)
    int*   ccnt = srcs + (size_t)B * F * CAP;               // B
    int*   tbin = ccnt + B;                                 // B
    int*   trank = tbin + B;                                // B

    const int zwords4 = (B * NBIN + 2 * B * F) / 4;         // 65536 int4
    kZ  <<<zwords4 / 256, 256, 0, stream>>>((int4*)hist);
    kW  <<<(B * F) / 4, 256, 0, stream>>>(feat, ring, w, hist);
    kT  <<<B, 256, 0, stream>>>(hist, tbin, trank, ccnt);
    kFL <<<(B * F) / 256, 256, 0, stream>>>(w, adj, tbin, flag, cnt, srcs, cand, ccnt);
    kSel<<<B, 1024, 0, stream>>>(ccnt, trank, cand, adj, flag, cnt, srcs);
    kG  <<<(B * F) / 4, 256, 0, stream>>>(feat, cnt, flag, srcs, out);
}

// Round 8
// 174.894 us; speedup vs baseline: 1.8439x; 1.8439x over previous
//
#include <hip/hip_runtime.h>
#include <stdint.h>

#define B 8
#define F 8192
#define C 256
#define K 4
#define P (F / 4)     // 2048
#define CAP 16        // max tracked incoming collapsed faces per target
#define NB 4096       // linear bins over [lo, hi]
#define NSLICE 4      // histogram slices per batch (32 kH blocks total)

// Monotone, deterministic linear bin — MUST be computed identically in kH/kFL.
__device__ __forceinline__ int binOf(float v, float lo, float scale) {
    int bin = (int)((v - lo) * scale);
    return bin < 0 ? 0 : (bin > NB - 1 ? NB - 1 : bin);
}

// ---------------------------------------------------------------------------
// kZ: zero cnt|flag (contiguous 512 KiB) with int4 stores; init min/max cell.
// ---------------------------------------------------------------------------
__global__ __launch_bounds__(256) void kZ(int4* __restrict__ z,
                                          unsigned int* __restrict__ mm) {
    const int i = blockIdx.x * 256 + threadIdx.x;
    z[i] = make_int4(0, 0, 0, 0);
    if (i == 0) { mm[0] = 0xFFFFFFFFu; mm[1] = 0u; }
}

// ---------------------------------------------------------------------------
// kW: one wave per face — gather K=4 ring rows, mean, L2 norm -> w.
// (R7 lesson: NO histogram atomics here — hot-bin serialization cost 110 us.)
// ---------------------------------------------------------------------------
__global__ __launch_bounds__(256) void kW(const float* __restrict__ feat,
                                          const int* __restrict__ ring,
                                          float* __restrict__ w) {
    const int wid  = blockIdx.x * 4 + (threadIdx.x >> 6);  // [0, B*F)
    const int lane = threadIdx.x & 63;
    const int b    = wid >> 13;

    const int rbase = wid * K;
    const int r0 = ring[rbase + 0], r1 = ring[rbase + 1];
    const int r2 = ring[rbase + 2], r3 = ring[rbase + 3];
    const float4* f4 = (const float4*)feat;
    const size_t base = (size_t)b * F;
    const int    CW   = C / 4;
    const float4 v0 = f4[(base + r0) * CW + lane];
    const float4 v1 = f4[(base + r1) * CW + lane];
    const float4 v2 = f4[(base + r2) * CW + lane];
    const float4 v3 = f4[(base + r3) * CW + lane];

    float4 a;
    a.x = (v0.x + v1.x) + (v2.x + v3.x);
    a.y = (v0.y + v1.y) + (v2.y + v3.y);
    a.z = (v0.z + v1.z) + (v2.z + v3.z);
    a.w = (v0.w + v1.w) + (v2.w + v3.w);
    float s = (a.x * a.x + a.y * a.y + a.z * a.z + a.w * a.w) * 0.0625f;
#pragma unroll
    for (int off = 32; off > 0; off >>= 1) s += __shfl_down(s, off, 64);
    if (lane == 0) w[wid] = sqrtf(s);
}

// ---------------------------------------------------------------------------
// kMM: device-wide exact min/max of w (uint trick, w >= 0). 8 blocks ->
// only 16 same-address atomics total.
// ---------------------------------------------------------------------------
__global__ __launch_bounds__(256) void kMM(const float* __restrict__ w,
                                           unsigned int* __restrict__ mm) {
    __shared__ unsigned int smn[256], smx[256];
    unsigned int mn = 0xFFFFFFFFu, mx = 0u;
    for (int i = blockIdx.x * 256 + threadIdx.x; i < B * F; i += 8 * 256) {
        const unsigned int u = __float_as_uint(w[i]);
        mn = mn < u ? mn : u;
        mx = mx > u ? mx : u;
    }
    smn[threadIdx.x] = mn; smx[threadIdx.x] = mx;
    __syncthreads();
    for (int off = 128; off > 0; off >>= 1) {
        if (threadIdx.x < off) {
            smn[threadIdx.x] = min(smn[threadIdx.x], smn[threadIdx.x + off]);
            smx[threadIdx.x] = max(smx[threadIdx.x], smx[threadIdx.x + off]);
        }
        __syncthreads();
    }
    if (threadIdx.x == 0) { atomicMin(&mm[0], smn[0]); atomicMax(&mm[1], smx[0]); }
}

// ---------------------------------------------------------------------------
// kH: 32 blocks, 2048 contiguous w values each. LDS histogram over 4096
// linear bins (max ~5 counts/bin/block -> negligible contention), then a
// PRIVATE full-slice write to global (no atomics, no pre-zero).
// ---------------------------------------------------------------------------
__global__ __launch_bounds__(256) void kH(const float* __restrict__ w,
                                          const unsigned int* __restrict__ mm,
                                          int* __restrict__ hist) {
    __shared__ int h[NB];                                   // 16 KiB
    for (int i = threadIdx.x; i < NB; i += 256) h[i] = 0;
    __syncthreads();
    const float lo    = __uint_as_float(mm[0]);
    const float hi    = __uint_as_float(mm[1]);
    const float scale = (float)(NB - 2) / fmaxf(hi - lo, 1e-30f);
    const int base = blockIdx.x * 2048;
#pragma unroll
    for (int k = 0; k < 8; ++k) {
        const float v = w[base + threadIdx.x + k * 256];
        atomicAdd(&h[binOf(v, lo, scale)], 1);
    }
    __syncthreads();
    int* slice = hist + (size_t)blockIdx.x * NB;
    for (int i = threadIdx.x; i < NB; i += 256) slice[i] = h[i];
}

// ---------------------------------------------------------------------------
// kT: per batch — sum NSLICE slices, scan 4096 bins -> threshold bin T (bin
// holding rank P-1) and R = P - count_below(T). Zeroes ccnt[b].
// ---------------------------------------------------------------------------
__global__ __launch_bounds__(1024) void kT(const int* __restrict__ hist,
                                           int* __restrict__ tbin,
                                           int* __restrict__ trank,
                                           int* __restrict__ ccnt) {
    __shared__ int hb[NB];                                  // 16 KiB
    __shared__ int part[1024];                              // 4 KiB
    const int b = blockIdx.x, t = threadIdx.x;
    if (t == 0) ccnt[b] = 0;
    const int* h0 = hist + (size_t)b * NSLICE * NB;
    int s = 0;
#pragma unroll
    for (int i = 0; i < 4; ++i) {
        const int bin = t * 4 + i;
        const int v = h0[bin] + h0[NB + bin] + h0[2 * NB + bin] + h0[3 * NB + bin];
        hb[bin] = v;
        s += v;
    }
    part[t] = s;
    __syncthreads();
    for (int off = 1; off < 1024; off <<= 1) {              // inclusive scan
        const int v = part[t];
        const int u = (t >= off) ? part[t - off] : 0;
        __syncthreads();
        part[t] = v + u;
        __syncthreads();
    }
    const int excl = (t == 0) ? 0 : part[t - 1];
    if (P - 1 >= excl && P - 1 < part[t]) {                 // exactly one thread
        int c = excl;
#pragma unroll
        for (int i = 0; i < 4; ++i) {
            const int bin = t * 4 + i;
            const int hv = hb[bin];
            if (P - 1 < c + hv) { tbin[b] = bin; trank[b] = P - c; break; }
            c += hv;
        }
    }
}

// ---------------------------------------------------------------------------
// kFL: 256 blocks, one per 256 faces of a single batch.
// bin < T  -> flag + push into 3 adjacency incoming lists.
// bin == T -> LDS-compact candidates, ONE ccnt atomic per block.
// ---------------------------------------------------------------------------
__global__ __launch_bounds__(256) void kFL(const float* __restrict__ w,
                                           const int* __restrict__ adj,
                                           const unsigned int* __restrict__ mm,
                                           const int* __restrict__ tbin,
                                           int* __restrict__ flag,
                                           int* __restrict__ cnt,
                                           int* __restrict__ srcs,
                                           unsigned long long* __restrict__ cand,
                                           int* __restrict__ ccnt) {
    __shared__ unsigned long long lc[256];
    __shared__ int lcnt;
    __shared__ int lbase;
    if (threadIdx.x == 0) lcnt = 0;
    __syncthreads();

    const float lo    = __uint_as_float(mm[0]);
    const float hi    = __uint_as_float(mm[1]);
    const float scale = (float)(NB - 2) / fmaxf(hi - lo, 1e-30f);

    const int t = blockIdx.x * 256 + threadIdx.x;           // [0, B*F)
    const int b = t >> 13;                                  // block spans one batch
    const float v = w[t];
    const int bin = binOf(v, lo, scale);
    const int T = tbin[b];
    if (bin < T) {
        flag[t] = 1;
#pragma unroll
        for (int j = 0; j < 3; ++j) {
            const int n    = adj[(size_t)t * 3 + j];
            const int tgt  = b * F + n;
            const int slot = atomicAdd(&cnt[tgt], 1);
            if (slot < CAP) srcs[(size_t)tgt * CAP + slot] = t;
        }
    } else if (bin == T) {
        const int pos = atomicAdd(&lcnt, 1);                // LDS atomic: cheap
        lc[pos] = ((unsigned long long)__float_as_uint(v) << 32) | (uint32_t)(t & (F - 1));
    }
    __syncthreads();
    if (threadIdx.x == 0 && lcnt > 0)
        lbase = atomicAdd(&ccnt[b], lcnt);                  // 1 contended op/block
    __syncthreads();
    const int m = lcnt;
    for (int i = threadIdx.x; i < m; i += 256)
        cand[(size_t)b * F + lbase + i] = lc[i];
}

// ---------------------------------------------------------------------------
// kSel: per batch — exact rank of boundary candidates by O(n^2) counting
// (keys distinct via idx bits; w>=0 so bit order == float order).
// rank < R -> flag + push. n ~ 20 with linear bins.
// ---------------------------------------------------------------------------
__global__ __launch_bounds__(1024) void kSel(const int* __restrict__ ccnt,
                                             const int* __restrict__ trank,
                                             const unsigned long long* __restrict__ cand,
                                             const int* __restrict__ adj,
                                             int* __restrict__ flag,
                                             int* __restrict__ cnt,
                                             int* __restrict__ srcs) {
    __shared__ unsigned long long keys[F];                  // 64 KiB
    const int b = blockIdx.x;
    const int n = ccnt[b];
    const int R = trank[b];
    for (int i = threadIdx.x; i < n; i += 1024)
        keys[i] = cand[(size_t)b * F + i];
    __syncthreads();
    for (int i = threadIdx.x; i < n; i += 1024) {
        const unsigned long long my = keys[i];
        int rank = 0;
        for (int j = 0; j < n; ++j) rank += (keys[j] < my) ? 1 : 0;
        if (rank < R) {
            const int t = b * F + (int)(uint32_t)my;
            flag[t] = 1;
#pragma unroll
            for (int j = 0; j < 3; ++j) {
                const int nb   = adj[(size_t)t * 3 + j];
                const int tgt  = b * F + nb;
                const int slot = atomicAdd(&cnt[tgt], 1);
                if (slot < CAP) srcs[(size_t)tgt * CAP + slot] = t;
            }
        }
    }
}

// ---------------------------------------------------------------------------
// kG: one wave per face — fused merge + normalize + erase.
// ---------------------------------------------------------------------------
__global__ __launch_bounds__(256) void kG(const float* __restrict__ feat,
                                          const int* __restrict__ cnt,
                                          const int* __restrict__ flag,
                                          const int* __restrict__ srcs,
                                          float* __restrict__ out) {
    const int wid  = blockIdx.x * 4 + (threadIdx.x >> 6);
    const int lane = threadIdx.x & 63;
    float4* drow = (float4*)(out + (size_t)wid * C);

    if (flag[wid]) {
        drow[lane] = make_float4(0.f, 0.f, 0.f, 0.f);
        return;
    }
    const int m  = cnt[wid];
    const int mm = m < CAP ? m : CAP;

    float4 acc = ((const float4*)(feat + (size_t)wid * C))[lane];
    const float inv3 = 1.0f / 3.0f;
    for (int i = 0; i < mm; ++i) {
        const int s = srcs[(size_t)wid * CAP + i];
        const float4 v = ((const float4*)(feat + (size_t)s * C))[lane];
        acc.x += v.x * inv3; acc.y += v.y * inv3;
        acc.z += v.z * inv3; acc.w += v.w * inv3;
    }
    const float inv = 1.0f / (1.0f + (float)m);
    acc.x *= inv; acc.y *= inv; acc.z *= inv; acc.w *= inv;
    drow[lane] = acc;
}

extern "C" void kernel_launch(void* const* d_in, const int* in_sizes, int n_in,
                              void* d_out, int out_size, void* d_ws, size_t ws_size,
                              hipStream_t stream) {
    const float* feat = (const float*)d_in[0];
    const int*   adj  = (const int*)d_in[1];
    const int*   ring = (const int*)d_in[2];
    float* out = (float*)d_out;

    // ws layout: cand (8B-aligned) | w | [cnt|flag] (contiguous for kZ) |
    //            hist | srcs | ccnt | tbin | trank | mm
    unsigned long long* cand = (unsigned long long*)d_ws;   // B*F (512 KiB)
    float* w     = (float*)(cand + B * F);                  // B*F
    int*   cnt   = (int*)(w + B * F);                       // B*F
    int*   flag  = cnt + B * F;                             // B*F
    int*   hist  = flag + B * F;                            // B*NSLICE*NB (512 KiB)
    int*   srcs  = hist + B * NSLICE * NB;                  // B*F*CAP (4 MiB)
    int*   ccnt  = srcs + (size_t)B * F * CAP;              // B
    int*   tbin  = ccnt + B;                                // B
    int*   trank = tbin + B;                                // B
    unsigned int* mm = (unsigned int*)(trank + B);          // 2

    kZ  <<<(2 * B * F / 4) / 256, 256, 0, stream>>>((int4*)cnt, mm);
    kW  <<<(B * F) / 4, 256, 0, stream>>>(feat, ring, w);
    kMM <<<8, 256, 0, stream>>>(w, mm);
    kH  <<<(B * F) / 2048, 256, 0, stream>>>(w, mm, hist);
    kT  <<<B, 1024, 0, stream>>>(hist, tbin, trank, ccnt);
    kFL <<<(B * F) / 256, 256, 0, stream>>>(w, adj, mm, tbin, flag, cnt, srcs, cand, ccnt);
    kSel<<<B, 1024, 0, stream>>>(ccnt, trank, cand, adj, flag, cnt, srcs);
    kG  <<<(B * F) / 4, 256, 0, stream>>>(feat, cnt, flag, srcs, out);
}

// Round 9
// 172.323 us; speedup vs baseline: 1.8714x; 1.0149x over previous
//
#include <hip/hip_runtime.h>
#include <stdint.h>

#define B 8
#define F 8192
#define C 256
#define K 4
#define P (F / 4)     // 2048
#define CAP 16        // max tracked incoming collapsed faces per target
#define NB 4096       // linear bins over [lo, hi]
#define NSLICE 4      // histogram slices per batch (32 kH blocks total)
#define MMB 8         // kMM blocks

// Monotone, deterministic linear bin — computed identically in kH and kFL.
__device__ __forceinline__ int binOf(float v, float lo, float scale) {
    int bin = (int)((v - lo) * scale);
    return bin < 0 ? 0 : (bin > NB - 1 ? NB - 1 : bin);
}

// Deterministic lo/scale from the 8 per-block min/max slots (same order in
// every consumer -> bit-identical results).
__device__ __forceinline__ void loScale(const unsigned int* bmn,
                                        const unsigned int* bmx,
                                        float& lo, float& scale) {
    unsigned int mn = 0xFFFFFFFFu, mx = 0u;
#pragma unroll
    for (int i = 0; i < MMB; ++i) {
        const unsigned int a = bmn[i], b = bmx[i];
        mn = mn < a ? mn : a;
        mx = mx > b ? mx : b;
    }
    lo = __uint_as_float(mn);
    const float hi = __uint_as_float(mx);
    scale = (float)(NB - 2) / fmaxf(hi - lo, 1e-30f);
}

// ---------------------------------------------------------------------------
// kW: one wave per face — gather K=4 ring rows, mean, L2 norm -> w.
// Lane 0 also zeroes cnt/flag for this face (replaces the kZ launch).
// (R7 lesson: NO histogram atomics here.)
// ---------------------------------------------------------------------------
__global__ __launch_bounds__(256) void kW(const float* __restrict__ feat,
                                          const int* __restrict__ ring,
                                          float* __restrict__ w,
                                          int* __restrict__ cnt,
                                          int* __restrict__ flag) {
    const int wid  = blockIdx.x * 4 + (threadIdx.x >> 6);  // [0, B*F)
    const int lane = threadIdx.x & 63;
    const int b    = wid >> 13;

    const int rbase = wid * K;
    const int r0 = ring[rbase + 0], r1 = ring[rbase + 1];
    const int r2 = ring[rbase + 2], r3 = ring[rbase + 3];
    const float4* f4 = (const float4*)feat;
    const size_t base = (size_t)b * F;
    const int    CW   = C / 4;
    const float4 v0 = f4[(base + r0) * CW + lane];
    const float4 v1 = f4[(base + r1) * CW + lane];
    const float4 v2 = f4[(base + r2) * CW + lane];
    const float4 v3 = f4[(base + r3) * CW + lane];

    float4 a;
    a.x = (v0.x + v1.x) + (v2.x + v3.x);
    a.y = (v0.y + v1.y) + (v2.y + v3.y);
    a.z = (v0.z + v1.z) + (v2.z + v3.z);
    a.w = (v0.w + v1.w) + (v2.w + v3.w);
    float s = (a.x * a.x + a.y * a.y + a.z * a.z + a.w * a.w) * 0.0625f;
#pragma unroll
    for (int off = 32; off > 0; off >>= 1) s += __shfl_down(s, off, 64);
    if (lane == 0) {
        w[wid]    = sqrtf(s);
        cnt[wid]  = 0;
        flag[wid] = 0;
    }
}

// ---------------------------------------------------------------------------
// kMM: per-block exact min/max of w (uint trick, w >= 0), PLAIN stores to
// private slots — no same-address atomics anywhere.
// ---------------------------------------------------------------------------
__global__ __launch_bounds__(256) void kMM(const float* __restrict__ w,
                                           unsigned int* __restrict__ bmn,
                                           unsigned int* __restrict__ bmx) {
    __shared__ unsigned int smn[256], smx[256];
    unsigned int mn = 0xFFFFFFFFu, mx = 0u;
    for (int i = blockIdx.x * 256 + threadIdx.x; i < B * F; i += MMB * 256) {
        const unsigned int u = __float_as_uint(w[i]);
        mn = mn < u ? mn : u;
        mx = mx > u ? mx : u;
    }
    smn[threadIdx.x] = mn; smx[threadIdx.x] = mx;
    __syncthreads();
    for (int off = 128; off > 0; off >>= 1) {
        if (threadIdx.x < off) {
            smn[threadIdx.x] = min(smn[threadIdx.x], smn[threadIdx.x + off]);
            smx[threadIdx.x] = max(smx[threadIdx.x], smx[threadIdx.x + off]);
        }
        __syncthreads();
    }
    if (threadIdx.x == 0) { bmn[blockIdx.x] = smn[0]; bmx[blockIdx.x] = smx[0]; }
}

// ---------------------------------------------------------------------------
// kH: 32 blocks, 2048 contiguous w values each. LDS histogram over 4096
// linear bins (≈5 counts/bin/block max -> negligible contention), PRIVATE
// full-slice store (no global atomics, no pre-zero).
// ---------------------------------------------------------------------------
__global__ __launch_bounds__(256) void kH(const float* __restrict__ w,
                                          const unsigned int* __restrict__ bmn,
                                          const unsigned int* __restrict__ bmx,
                                          int* __restrict__ hist) {
    __shared__ int h[NB];                                   // 16 KiB
    for (int i = threadIdx.x; i < NB; i += 256) h[i] = 0;
    __syncthreads();
    float lo, scale;
    loScale(bmn, bmx, lo, scale);
    const int base = blockIdx.x * 2048;
#pragma unroll
    for (int k = 0; k < 8; ++k) {
        const float v = w[base + threadIdx.x + k * 256];
        atomicAdd(&h[binOf(v, lo, scale)], 1);
    }
    __syncthreads();
    int* slice = hist + (size_t)blockIdx.x * NB;
    for (int i = threadIdx.x; i < NB; i += 256) slice[i] = h[i];
}

// ---------------------------------------------------------------------------
// kT: per batch — sum NSLICE slices, scan 4096 bins -> threshold bin T (bin
// holding rank P-1) and R = P - count_below(T). Zeroes ccnt[b].
// ---------------------------------------------------------------------------
__global__ __launch_bounds__(1024) void kT(const int* __restrict__ hist,
                                           int* __restrict__ tbin,
                                           int* __restrict__ trank,
                                           int* __restrict__ ccnt) {
    __shared__ int hb[NB];                                  // 16 KiB
    __shared__ int part[1024];                              // 4 KiB
    const int b = blockIdx.x, t = threadIdx.x;
    if (t == 0) ccnt[b] = 0;
    const int* h0 = hist + (size_t)b * NSLICE * NB;
    int s = 0;
#pragma unroll
    for (int i = 0; i < 4; ++i) {
        const int bin = t * 4 + i;
        const int v = h0[bin] + h0[NB + bin] + h0[2 * NB + bin] + h0[3 * NB + bin];
        hb[bin] = v;
        s += v;
    }
    part[t] = s;
    __syncthreads();
    for (int off = 1; off < 1024; off <<= 1) {              // inclusive scan
        const int v = part[t];
        const int u = (t >= off) ? part[t - off] : 0;
        __syncthreads();
        part[t] = v + u;
        __syncthreads();
    }
    const int excl = (t == 0) ? 0 : part[t - 1];
    if (P - 1 >= excl && P - 1 < part[t]) {                 // exactly one thread
        int c = excl;
#pragma unroll
        for (int i = 0; i < 4; ++i) {
            const int bin = t * 4 + i;
            const int hv = hb[bin];
            if (P - 1 < c + hv) { tbin[b] = bin; trank[b] = P - c; break; }
            c += hv;
        }
    }
}

// ---------------------------------------------------------------------------
// kFL: 256 blocks, one per 256 faces of a single batch.
// bin < T  -> flag + push into 3 adjacency incoming lists.
// bin == T -> LDS-compact candidates, ONE ccnt atomic per block.
// ---------------------------------------------------------------------------
__global__ __launch_bounds__(256) void kFL(const float* __restrict__ w,
                                           const int* __restrict__ adj,
                                           const unsigned int* __restrict__ bmn,
                                           const unsigned int* __restrict__ bmx,
                                           const int* __restrict__ tbin,
                                           int* __restrict__ flag,
                                           int* __restrict__ cnt,
                                           int* __restrict__ srcs,
                                           unsigned long long* __restrict__ cand,
                                           int* __restrict__ ccnt) {
    __shared__ unsigned long long lc[256];
    __shared__ int lcnt;
    __shared__ int lbase;
    if (threadIdx.x == 0) lcnt = 0;
    __syncthreads();

    float lo, scale;
    loScale(bmn, bmx, lo, scale);

    const int t = blockIdx.x * 256 + threadIdx.x;           // [0, B*F)
    const int b = t >> 13;                                  // block spans one batch
    const float v = w[t];
    const int bin = binOf(v, lo, scale);
    const int T = tbin[b];
    if (bin < T) {
        flag[t] = 1;
#pragma unroll
        for (int j = 0; j < 3; ++j) {
            const int n    = adj[(size_t)t * 3 + j];
            const int tgt  = b * F + n;
            const int slot = atomicAdd(&cnt[tgt], 1);
            if (slot < CAP) srcs[(size_t)tgt * CAP + slot] = t;
        }
    } else if (bin == T) {
        const int pos = atomicAdd(&lcnt, 1);                // LDS atomic: cheap
        lc[pos] = ((unsigned long long)__float_as_uint(v) << 32) | (uint32_t)(t & (F - 1));
    }
    __syncthreads();
    if (threadIdx.x == 0 && lcnt > 0)
        lbase = atomicAdd(&ccnt[b], lcnt);                  // 1 contended op/block
    __syncthreads();
    const int m = lcnt;
    for (int i = threadIdx.x; i < m; i += 256)
        cand[(size_t)b * F + lbase + i] = lc[i];
}

// ---------------------------------------------------------------------------
// kSel: per batch — exact rank of boundary candidates by O(n^2) counting
// (keys distinct via idx bits; w>=0 so bit order == float order).
// rank < R -> flag + push. n ~ 20 with linear bins.
// ---------------------------------------------------------------------------
__global__ __launch_bounds__(1024) void kSel(const int* __restrict__ ccnt,
                                             const int* __restrict__ trank,
                                             const unsigned long long* __restrict__ cand,
                                             const int* __restrict__ adj,
                                             int* __restrict__ flag,
                                             int* __restrict__ cnt,
                                             int* __restrict__ srcs) {
    __shared__ unsigned long long keys[F];                  // 64 KiB
    const int b = blockIdx.x;
    const int n = ccnt[b];
    const int R = trank[b];
    for (int i = threadIdx.x; i < n; i += 1024)
        keys[i] = cand[(size_t)b * F + i];
    __syncthreads();
    for (int i = threadIdx.x; i < n; i += 1024) {
        const unsigned long long my = keys[i];
        int rank = 0;
        for (int j = 0; j < n; ++j) rank += (keys[j] < my) ? 1 : 0;
        if (rank < R) {
            const int t = b * F + (int)(uint32_t)my;
            flag[t] = 1;
#pragma unroll
            for (int j = 0; j < 3; ++j) {
                const int nb   = adj[(size_t)t * 3 + j];
                const int tgt  = b * F + nb;
                const int slot = atomicAdd(&cnt[tgt], 1);
                if (slot < CAP) srcs[(size_t)tgt * CAP + slot] = t;
            }
        }
    }
}

// ---------------------------------------------------------------------------
// kG: one wave per face — fused merge + normalize + erase.
// src indices fetched coalesced by lanes 0..15 then __shfl-broadcast: the
// incoming-row loop body has no scalar-load dependency chain.
// ---------------------------------------------------------------------------
__global__ __launch_bounds__(256) void kG(const float* __restrict__ feat,
                                          const int* __restrict__ cnt,
                                          const int* __restrict__ flag,
                                          const int* __restrict__ srcs,
                                          float* __restrict__ out) {
    const int wid  = blockIdx.x * 4 + (threadIdx.x >> 6);
    const int lane = threadIdx.x & 63;
    float4* drow = (float4*)(out + (size_t)wid * C);

    if (flag[wid]) {                                        // wave-uniform branch
        drow[lane] = make_float4(0.f, 0.f, 0.f, 0.f);
        return;
    }
    const int m  = cnt[wid];
    const int mm = m < CAP ? m : CAP;

    const int sidx = (lane < CAP) ? srcs[(size_t)wid * CAP + lane] : 0;

    float4 acc = ((const float4*)(feat + (size_t)wid * C))[lane];
    const float inv3 = 1.0f / 3.0f;
    for (int i = 0; i < mm; ++i) {
        const int s = __shfl(sidx, i, 64);
        const float4 v = ((const float4*)(feat + (size_t)s * C))[lane];
        acc.x += v.x * inv3; acc.y += v.y * inv3;
        acc.z += v.z * inv3; acc.w += v.w * inv3;
    }
    const float inv = 1.0f / (1.0f + (float)m);
    acc.x *= inv; acc.y *= inv; acc.z *= inv; acc.w *= inv;
    drow[lane] = acc;
}

extern "C" void kernel_launch(void* const* d_in, const int* in_sizes, int n_in,
                              void* d_out, int out_size, void* d_ws, size_t ws_size,
                              hipStream_t stream) {
    const float* feat = (const float*)d_in[0];
    const int*   adj  = (const int*)d_in[1];
    const int*   ring = (const int*)d_in[2];
    float* out = (float*)d_out;

    // ws layout: cand (8B-aligned) | w | cnt | flag | hist | srcs |
    //            ccnt | tbin | trank | bmn | bmx
    unsigned long long* cand = (unsigned long long*)d_ws;   // B*F (512 KiB)
    float* w     = (float*)(cand + B * F);                  // B*F
    int*   cnt   = (int*)(w + B * F);                       // B*F
    int*   flag  = cnt + B * F;                             // B*F
    int*   hist  = flag + B * F;                            // B*NSLICE*NB (512 KiB)
    int*   srcs  = hist + B * NSLICE * NB;                  // B*F*CAP (4 MiB)
    int*   ccnt  = srcs + (size_t)B * F * CAP;              // B
    int*   tbin  = ccnt + B;                                // B
    int*   trank = tbin + B;                                // B
    unsigned int* bmn = (unsigned int*)(trank + B);         // MMB
    unsigned int* bmx = bmn + MMB;                          // MMB

    kW  <<<(B * F) / 4, 256, 0, stream>>>(feat, ring, w, cnt, flag);
    kMM <<<MMB, 256, 0, stream>>>(w, bmn, bmx);
    kH  <<<(B * F) / 2048, 256, 0, stream>>>(w, bmn, bmx, hist);
    kT  <<<B, 1024, 0, stream>>>(hist, tbin, trank, ccnt);
    kFL <<<(B * F) / 256, 256, 0, stream>>>(w, adj, bmn, bmx, tbin, flag, cnt, srcs, cand, ccnt);
    kSel<<<B, 1024, 0, stream>>>(ccnt, trank, cand, adj, flag, cnt, srcs);
    kG  <<<(B * F) / 4, 256, 0, stream>>>(feat, cnt, flag, srcs, out);
}

// Round 10
// 162.553 us; speedup vs baseline: 1.9839x; 1.0601x over previous
//
#include <hip/hip_runtime.h>
#include <stdint.h>

#define B 8
#define F 8192
#define C 256
#define K 4
#define P (F / 4)     // 2048
#define CAP 16        // max tracked incoming collapsed faces per target
#define NB 4096       // linear bins over per-batch [lo, hi]

// Monotone, deterministic linear bin — computed identically in kHT and kFL.
__device__ __forceinline__ int binOf(float v, float lo, float scale) {
    int bin = (int)((v - lo) * scale);
    return bin < 0 ? 0 : (bin > NB - 1 ? NB - 1 : bin);
}

// ---------------------------------------------------------------------------
// kW: one wave per face — gather K=4 ring rows, mean, L2 norm -> w.
// Lane 0 zeroes cnt/flag. Block->batch swizzle: blockIdx&7 = batch, so each
// XCD's L2 serves ONE batch's 8 MB feat slice instead of all 64 MB.
// (R7 lesson: NO histogram atomics here.)
// ---------------------------------------------------------------------------
__global__ __launch_bounds__(256) void kW(const float* __restrict__ feat,
                                          const int* __restrict__ ring,
                                          float* __restrict__ w,
                                          int* __restrict__ cnt,
                                          int* __restrict__ flag) {
    const int b     = blockIdx.x & 7;                       // batch == XCD
    const int inner = blockIdx.x >> 3;                      // [0, 2048)
    const int wid   = b * F + inner * 4 + (threadIdx.x >> 6);
    const int lane  = threadIdx.x & 63;

    const int rbase = wid * K;
    const int r0 = ring[rbase + 0], r1 = ring[rbase + 1];
    const int r2 = ring[rbase + 2], r3 = ring[rbase + 3];
    const float4* f4 = (const float4*)feat;
    const size_t base = (size_t)b * F;
    const int    CW   = C / 4;
    const float4 v0 = f4[(base + r0) * CW + lane];
    const float4 v1 = f4[(base + r1) * CW + lane];
    const float4 v2 = f4[(base + r2) * CW + lane];
    const float4 v3 = f4[(base + r3) * CW + lane];

    float4 a;
    a.x = (v0.x + v1.x) + (v2.x + v3.x);
    a.y = (v0.y + v1.y) + (v2.y + v3.y);
    a.z = (v0.z + v1.z) + (v2.z + v3.z);
    a.w = (v0.w + v1.w) + (v2.w + v3.w);
    float s = (a.x * a.x + a.y * a.y + a.z * a.z + a.w * a.w) * 0.0625f;
#pragma unroll
    for (int off = 32; off > 0; off >>= 1) s += __shfl_down(s, off, 64);
    if (lane == 0) {
        w[wid]    = sqrtf(s);
        cnt[wid]  = 0;
        flag[wid] = 0;
    }
}

// ---------------------------------------------------------------------------
// kHT: ONE block (1024 thr) per batch — fused min/max + 4096-bin linear
// histogram + scan -> threshold bin T, rank R. Replaces kMM+kH+kT (3
// dispatches -> 1). Stores lo/hi bits so kFL recomputes scale identically.
// Per-batch bins: width ~0.0007 -> threshold-bin population ~7 (kSel trivial).
// ---------------------------------------------------------------------------
__global__ __launch_bounds__(1024) void kHT(const float* __restrict__ w,
                                            int* __restrict__ tbin,
                                            int* __restrict__ trank,
                                            int* __restrict__ ccnt,
                                            unsigned int* __restrict__ lsb) {
    __shared__ int h[NB];                                   // 16 KiB
    __shared__ unsigned int red[1024];                      // 4 KiB (reduce+scan)
    const int b = blockIdx.x, t = threadIdx.x;

    // load 8 values/thread, coalesced; per-thread min/max
    float val[8];
    unsigned int mn = 0xFFFFFFFFu, mx = 0u;
#pragma unroll
    for (int k = 0; k < 8; ++k) {
        val[k] = w[b * F + t + k * 1024];
        const unsigned int u = __float_as_uint(val[k]);     // w>=0: bit-monotone
        mn = mn < u ? mn : u;
        mx = mx > u ? mx : u;
    }
    red[t] = mn;
    __syncthreads();
    for (int off = 512; off > 0; off >>= 1) {
        if (t < off) red[t] = min(red[t], red[t + off]);
        __syncthreads();
    }
    const unsigned int lob = red[0];
    __syncthreads();
    red[t] = mx;
    __syncthreads();
    for (int off = 512; off > 0; off >>= 1) {
        if (t < off) red[t] = max(red[t], red[t + off]);
        __syncthreads();
    }
    const unsigned int hib = red[0];
    __syncthreads();

    const float lo    = __uint_as_float(lob);
    const float hi    = __uint_as_float(hib);
    const float scale = (float)(NB - 2) / fmaxf(hi - lo, 1e-30f);

    // histogram (max ~7 hits/bin -> negligible LDS-atomic contention)
    for (int i = t; i < NB; i += 1024) h[i] = 0;
    __syncthreads();
#pragma unroll
    for (int k = 0; k < 8; ++k) atomicAdd(&h[binOf(val[k], lo, scale)], 1);
    __syncthreads();

    // inclusive scan over 1024 partials (4 bins/thread)
    int s = 0;
#pragma unroll
    for (int i = 0; i < 4; ++i) s += h[t * 4 + i];
    int* part = (int*)red;
    part[t] = s;
    __syncthreads();
    for (int off = 1; off < 1024; off <<= 1) {
        const int v = part[t];
        const int u = (t >= off) ? part[t - off] : 0;
        __syncthreads();
        part[t] = v + u;
        __syncthreads();
    }
    const int excl = (t == 0) ? 0 : part[t - 1];
    if (P - 1 >= excl && P - 1 < part[t]) {                 // exactly one thread
        int c = excl;
#pragma unroll
        for (int i = 0; i < 4; ++i) {
            const int bin = t * 4 + i;
            const int hv = h[bin];
            if (P - 1 < c + hv) { tbin[b] = bin; trank[b] = P - c; break; }
            c += hv;
        }
    }
    if (t == 0) {
        ccnt[b] = 0;
        lsb[b * 2 + 0] = lob;
        lsb[b * 2 + 1] = hib;
    }
}

// ---------------------------------------------------------------------------
// kFL: 256 blocks, one per 256 faces of a single batch.
// bin < T  -> flag + push into 3 adjacency incoming lists.
// bin == T -> LDS-compact candidates, ONE ccnt atomic per block.
// ---------------------------------------------------------------------------
__global__ __launch_bounds__(256) void kFL(const float* __restrict__ w,
                                           const int* __restrict__ adj,
                                           const unsigned int* __restrict__ lsb,
                                           const int* __restrict__ tbin,
                                           int* __restrict__ flag,
                                           int* __restrict__ cnt,
                                           int* __restrict__ srcs,
                                           unsigned long long* __restrict__ cand,
                                           int* __restrict__ ccnt) {
    __shared__ unsigned long long lc[256];
    __shared__ int lcnt;
    __shared__ int lbase;
    if (threadIdx.x == 0) lcnt = 0;
    __syncthreads();

    const int t = blockIdx.x * 256 + threadIdx.x;           // [0, B*F)
    const int b = t >> 13;                                  // block spans one batch
    const float lo    = __uint_as_float(lsb[b * 2 + 0]);
    const float hi    = __uint_as_float(lsb[b * 2 + 1]);
    const float scale = (float)(NB - 2) / fmaxf(hi - lo, 1e-30f);

    const float v = w[t];
    const int bin = binOf(v, lo, scale);
    const int T = tbin[b];
    if (bin < T) {
        flag[t] = 1;
#pragma unroll
        for (int j = 0; j < 3; ++j) {
            const int n    = adj[(size_t)t * 3 + j];
            const int tgt  = b * F + n;
            const int slot = atomicAdd(&cnt[tgt], 1);
            if (slot < CAP) srcs[(size_t)tgt * CAP + slot] = t;
        }
    } else if (bin == T) {
        const int pos = atomicAdd(&lcnt, 1);                // LDS atomic: cheap
        lc[pos] = ((unsigned long long)__float_as_uint(v) << 32) | (uint32_t)(t & (F - 1));
    }
    __syncthreads();
    if (threadIdx.x == 0 && lcnt > 0)
        lbase = atomicAdd(&ccnt[b], lcnt);                  // 1 contended op/block
    __syncthreads();
    const int m = lcnt;
    for (int i = threadIdx.x; i < m; i += 256)
        cand[(size_t)b * F + lbase + i] = lc[i];
}

// ---------------------------------------------------------------------------
// kSel: per batch — exact rank of boundary candidates by O(n^2) counting
// (keys distinct via idx bits; w>=0 so bit order == float order).
// rank < R -> flag + push. n ~ 7 with per-batch linear bins.
// ---------------------------------------------------------------------------
__global__ __launch_bounds__(1024) void kSel(const int* __restrict__ ccnt,
                                             const int* __restrict__ trank,
                                             const unsigned long long* __restrict__ cand,
                                             const int* __restrict__ adj,
                                             int* __restrict__ flag,
                                             int* __restrict__ cnt,
                                             int* __restrict__ srcs) {
    __shared__ unsigned long long keys[F];                  // 64 KiB
    const int b = blockIdx.x;
    const int n = ccnt[b];
    const int R = trank[b];
    for (int i = threadIdx.x; i < n; i += 1024)
        keys[i] = cand[(size_t)b * F + i];
    __syncthreads();
    for (int i = threadIdx.x; i < n; i += 1024) {
        const unsigned long long my = keys[i];
        int rank = 0;
        for (int j = 0; j < n; ++j) rank += (keys[j] < my) ? 1 : 0;
        if (rank < R) {
            const int t = b * F + (int)(uint32_t)my;
            flag[t] = 1;
#pragma unroll
            for (int j = 0; j < 3; ++j) {
                const int nb   = adj[(size_t)t * 3 + j];
                const int tgt  = b * F + nb;
                const int slot = atomicAdd(&cnt[tgt], 1);
                if (slot < CAP) srcs[(size_t)tgt * CAP + slot] = t;
            }
        }
    }
}

// ---------------------------------------------------------------------------
// kG: one wave per face — fused merge + normalize + erase, same batch<->XCD
// swizzle as kW (incoming-src gathers are batch-local).
// ---------------------------------------------------------------------------
__global__ __launch_bounds__(256) void kG(const float* __restrict__ feat,
                                          const int* __restrict__ cnt,
                                          const int* __restrict__ flag,
                                          const int* __restrict__ srcs,
                                          float* __restrict__ out) {
    const int b     = blockIdx.x & 7;                       // batch == XCD
    const int inner = blockIdx.x >> 3;
    const int wid   = b * F + inner * 4 + (threadIdx.x >> 6);
    const int lane  = threadIdx.x & 63;
    float4* drow = (float4*)(out + (size_t)wid * C);

    if (flag[wid]) {                                        // wave-uniform branch
        drow[lane] = make_float4(0.f, 0.f, 0.f, 0.f);
        return;
    }
    const int m  = cnt[wid];
    const int mm = m < CAP ? m : CAP;

    const int sidx = (lane < CAP) ? srcs[(size_t)wid * CAP + lane] : 0;

    float4 acc = ((const float4*)(feat + (size_t)wid * C))[lane];
    const float inv3 = 1.0f / 3.0f;
    for (int i = 0; i < mm; ++i) {
        const int s = __shfl(sidx, i, 64);
        const float4 v = ((const float4*)(feat + (size_t)s * C))[lane];
        acc.x += v.x * inv3; acc.y += v.y * inv3;
        acc.z += v.z * inv3; acc.w += v.w * inv3;
    }
    const float inv = 1.0f / (1.0f + (float)m);
    acc.x *= inv; acc.y *= inv; acc.z *= inv; acc.w *= inv;
    drow[lane] = acc;
}

extern "C" void kernel_launch(void* const* d_in, const int* in_sizes, int n_in,
                              void* d_out, int out_size, void* d_ws, size_t ws_size,
                              hipStream_t stream) {
    const float* feat = (const float*)d_in[0];
    const int*   adj  = (const int*)d_in[1];
    const int*   ring = (const int*)d_in[2];
    float* out = (float*)d_out;

    // ws layout: cand (8B-aligned) | w | cnt | flag | srcs | ccnt | tbin |
    //            trank | lsb
    unsigned long long* cand = (unsigned long long*)d_ws;   // B*F (512 KiB)
    float* w     = (float*)(cand + B * F);                  // B*F
    int*   cnt   = (int*)(w + B * F);                       // B*F
    int*   flag  = cnt + B * F;                             // B*F
    int*   srcs  = flag + B * F;                            // B*F*CAP (4 MiB)
    int*   ccnt  = srcs + (size_t)B * F * CAP;              // B
    int*   tbin  = ccnt + B;                                // B
    int*   trank = tbin + B;                                // B
    unsigned int* lsb = (unsigned int*)(trank + B);         // 2*B

    kW  <<<(B * F) / 4, 256, 0, stream>>>(feat, ring, w, cnt, flag);
    kHT <<<B, 1024, 0, stream>>>(w, tbin, trank, ccnt, lsb);
    kFL <<<(B * F) / 256, 256, 0, stream>>>(w, adj, lsb, tbin, flag, cnt, srcs, cand, ccnt);
    kSel<<<B, 1024, 0, stream>>>(ccnt, trank, cand, adj, flag, cnt, srcs);
    kG  <<<(B * F) / 4, 256, 0, stream>>>(feat, cnt, flag, srcs, out);
}